// Round 3
// baseline (540.975 us; speedup 1.0000x reference)
//
#include <hip/hip_runtime.h>
#include <stdint.h>

typedef __attribute__((ext_vector_type(4))) float f32x4;
typedef __attribute__((ext_vector_type(8))) short s16x8;

#define CC   192
#define NN   16384
#define EE   4
#define HIDD 384

// LDS map (dynamic, 50176 B) -> 3 blocks/CU:
//  [0,     24576)  X tile [64][192] bf16 swizzled; AFTER frag hoist reused as hid buf0
//  [24576, 49152)  router partials (phase 1-2 only), then hid buf1
//  [49152, 50176)  gates [64 tok][4 e] f32
//  epilogue: outl [192 c][65 tok] f32 = 49920 B overlays everything (gates read to regs first)
#define OFF_H0   0u
#define OFF_H1   24576u
#define OFF_PART 24576
#define OFF_GATE 49152
#define LDS_SZ   50176

__device__ __forceinline__ uint16_t bfbits(float f){
  uint32_t u = __builtin_bit_cast(uint32_t, f);
  u += 0x7FFFu + ((u >> 16) & 1u);
  return (uint16_t)(u >> 16);
}
__device__ __forceinline__ uint32_t pkbf(float lo, float hi){
  uint32_t ul = __builtin_bit_cast(uint32_t, lo);
  uint32_t uh = __builtin_bit_cast(uint32_t, hi);
  ul += 0x7FFFu + ((ul >> 16) & 1u);
  uh += 0x7FFFu + ((uh >> 16) & 1u);
  return (ul >> 16) | (uh & 0xFFFF0000u);
}
// tanh-form GELU, |err| <= ~3e-3 (threshold 0.109; measured absmax 0.031 with this)
__device__ __forceinline__ float gelu_f(float v){
  float x2 = v * v;
  float z = v * __builtin_fmaf(x2, -0.1029432f, -2.3022082f);
  float e = __builtin_amdgcn_exp2f(z);
  return v * __builtin_amdgcn_rcpf(1.0f + e);
}
__device__ __forceinline__ f32x4 mfma16(s16x8 a, s16x8 b, f32x4 c){
  asm("v_mfma_f32_16x16x32_bf16 %0, %1, %2, %0" : "+v"(c) : "v"(a), "v"(b));
  return c;
}

extern "C" __global__ void kconv(const float* __restrict__ w1, const float* __restrict__ w2,
                                 uint16_t* __restrict__ w1b, uint16_t* __restrict__ w2b){
  int i = blockIdx.x * 256 + threadIdx.x;
  w1b[i] = bfbits(w1[i]);
  w2b[i] = bfbits(w2[i]);
}

// 1 block = 64 tokens, 256 threads = 4 waves; waves split the feature dim.
// A-operand = weights, B-operand = activations; D = [feature][token].
__global__ __launch_bounds__(256, 3) void kmoe(
    const float* __restrict__ x, const float* __restrict__ rw,
    const float* __restrict__ rb, const uint16_t* __restrict__ w1b,
    const float* __restrict__ b1, const uint16_t* __restrict__ w2b,
    const float* __restrict__ b2, const float* __restrict__ scp,
    float* __restrict__ out)
{
  extern __shared__ __align__(16) unsigned char S[];
  const int tid  = threadIdx.x;
  const int lane = tid & 63;
  const int wv   = tid >> 6;
  const int lq   = lane & 15;
  const int lg   = lane >> 4;
  const int tile = blockIdx.x;
  const int b    = tile >> 8;
  const int n0   = (tile & 255) << 6;
  const float* xb = x + (size_t)b * CC * NN;

  // ---- Phase 1: stage X tile (bf16, swizzled) + fp32 router partials
  {
    const int t = lane;
    const uint32_t rowb = (uint32_t)t * 384u;
    const uint32_t sw   = ((uint32_t)(t & 7)) << 4;
    float a0 = 0.f, a1 = 0.f, a2 = 0.f, a3 = 0.f;
    #pragma unroll 8
    for (int j = 0; j < 48; j += 2){
      const int c = wv * 48 + j;
      const float v0 = xb[(size_t)c * NN + n0 + t];
      const float v1 = xb[(size_t)(c + 1) * NN + n0 + t];
      a0 = __builtin_fmaf(v1, rw[c + 1],          __builtin_fmaf(v0, rw[c],          a0));
      a1 = __builtin_fmaf(v1, rw[CC + c + 1],     __builtin_fmaf(v0, rw[CC + c],     a1));
      a2 = __builtin_fmaf(v1, rw[2 * CC + c + 1], __builtin_fmaf(v0, rw[2 * CC + c], a2));
      a3 = __builtin_fmaf(v1, rw[3 * CC + c + 1], __builtin_fmaf(v0, rw[3 * CC + c], a3));
      *(uint32_t*)(S + rowb + (((uint32_t)(2 * c)) ^ sw)) = pkbf(v0, v1);
    }
    float* pl = (float*)(S + OFF_PART);
    pl[(wv * 4 + 0) * 64 + t] = a0;
    pl[(wv * 4 + 1) * 64 + t] = a1;
    pl[(wv * 4 + 2) * 64 + t] = a2;
    pl[(wv * 4 + 3) * 64 + t] = a3;
  }
  __syncthreads();

  // ---- Phase 2 (tid<64): router finalize -> gates
  if (tid < 64){
    const int t = tid;
    const float* pl = (const float*)(S + OFF_PART);
    float l0 = rb[0], l1 = rb[1], l2 = rb[2], l3 = rb[3];
    #pragma unroll
    for (int cg = 0; cg < 4; ++cg){
      l0 += pl[(cg * 4 + 0) * 64 + t];
      l1 += pl[(cg * 4 + 1) * 64 + t];
      l2 += pl[(cg * 4 + 2) * 64 + t];
      l3 += pl[(cg * 4 + 3) * 64 + t];
    }
    int i1 = 0; float v1 = l0;
    if (l1 > v1){ v1 = l1; i1 = 1; }
    if (l2 > v1){ v1 = l2; i1 = 2; }
    if (l3 > v1){ v1 = l3; i1 = 3; }
    float v2 = -3.0e38f; int i2 = 0;
    if (i1 != 0){ v2 = l0; i2 = 0; }
    if (i1 != 1 && l1 > v2){ v2 = l1; i2 = 1; }
    if (i1 != 2 && l2 > v2){ v2 = l2; i2 = 2; }
    if (i1 != 3 && l3 > v2){ v2 = l3; i2 = 3; }
    const float ex = __expf(v2 - v1);
    const float ga = 1.0f / (1.0f + ex);
    const float gb = ex * ga;
    float* glw = (float*)(S + OFF_GATE);
    glw[t * 4 + 0] = (i1 == 0) ? ga : ((i2 == 0) ? gb : 0.0f);
    glw[t * 4 + 1] = (i1 == 1) ? ga : ((i2 == 1) ? gb : 0.0f);
    glw[t * 4 + 2] = (i1 == 2) ? ga : ((i2 == 2) ? gb : 0.0f);
    glw[t * 4 + 3] = (i1 == 3) ? ga : ((i2 == 3) ? gb : 0.0f);
  }

  // X B-fragments -> registers (invariant across all (e,ch)): 24 x s16x8 = 96 VGPR
  const uint32_t xsw = ((uint32_t)(lq & 7)) << 4;
  s16x8 xf[4][6];
  #pragma unroll
  for (int np = 0; np < 4; ++np){
    const uint32_t rowb = (uint32_t)(16 * np + lq) * 384u;
    #pragma unroll
    for (int kk = 0; kk < 6; ++kk)
      xf[np][kk] = *(const s16x8*)(S + rowb + (((uint32_t)(64 * kk + 16 * lg)) ^ xsw));
  }
  __syncthreads();   // X reads + partials reads done -> regions reusable as hid bufs

  // ---- Main loop: 8 iterations (e x ch), 1 barrier each (hid double-buffered)
  const float* gl = (const float*)(S + OFF_GATE);
  const uint16_t* w1t = w1b + (size_t)(wv * 48 + lq) * CC   + 8 * lg;
  const uint16_t* w2t = w2b + (size_t)(wv * 48 + lq) * HIDD + 8 * lg;

  f32x4 oacc[3][4];
  #pragma unroll
  for (int m = 0; m < 3; ++m)
    #pragma unroll
    for (int np = 0; np < 4; ++np)
      oacc[m][np] = (f32x4){0.f, 0.f, 0.f, 0.f};

  #pragma unroll 1
  for (int e = 0; e < EE; ++e){
    float gt[4];
    #pragma unroll
    for (int np = 0; np < 4; ++np) gt[np] = gl[(16 * np + lq) * 4 + e];
    #pragma unroll 1
    for (int ch = 0; ch < 2; ++ch){
      const uint32_t hb = ((e * 2 + ch) & 1) ? OFF_H1 : OFF_H0;
      // GEMM1: hacc[hid-tile][tok-tile], init from fc1 bias (4 consecutive features/lane)
      f32x4 hacc[3][4];
      #pragma unroll
      for (int m = 0; m < 3; ++m){
        const f32x4 bv = *(const f32x4*)(b1 + e * HIDD + ch * 192 + wv * 48 + 16 * m + 4 * lg);
        #pragma unroll
        for (int np = 0; np < 4; ++np) hacc[m][np] = bv;
      }
      const uint16_t* w1p = w1t + (size_t)(e * HIDD + ch * 192) * CC;
      #pragma unroll
      for (int kk = 0; kk < 6; ++kk){
        s16x8 wf[3];
        #pragma unroll
        for (int m = 0; m < 3; ++m)
          wf[m] = *(const s16x8*)(w1p + (size_t)(16 * m) * CC + kk * 32);
        #pragma unroll
        for (int np = 0; np < 4; ++np)
          #pragma unroll
          for (int m = 0; m < 3; ++m)
            hacc[m][np] = mfma16(wf[m], xf[np][kk], hacc[m][np]);
      }
      // Prefetch GEMM2 kk=0 weight frags: L2 latency hides under gelu + barrier
      const uint16_t* w2p = w2t + (size_t)(e * CC) * HIDD + ch * 192;
      s16x8 wpre[3];
      #pragma unroll
      for (int m = 0; m < 3; ++m)
        wpre[m] = *(const s16x8*)(w2p + (size_t)(16 * m) * HIDD);
      // GELU * gate -> hid LDS (b64 writes: 4 consecutive features per lane)
      #pragma unroll
      for (int np = 0; np < 4; ++np){
        const uint32_t tb = hb + (uint32_t)(16 * np + lq) * 384u;
        const float g = gt[np];
        #pragma unroll
        for (int m = 0; m < 3; ++m){
          const float v0 = gelu_f(hacc[m][np][0]) * g;
          const float v1 = gelu_f(hacc[m][np][1]) * g;
          const float v2 = gelu_f(hacc[m][np][2]) * g;
          const float v3 = gelu_f(hacc[m][np][3]) * g;
          uint2 p; p.x = pkbf(v0, v1); p.y = pkbf(v2, v3);
          *(uint2*)(S + tb + (((uint32_t)(96 * wv + 32 * m + 8 * lg)) ^ xsw)) = p;
        }
      }
      __syncthreads();
      // GEMM2: A = fc2 rows (C channels), B = hid from LDS
      #pragma unroll
      for (int kk = 0; kk < 6; ++kk){
        s16x8 wf[3], hf[4];
        #pragma unroll
        for (int m = 0; m < 3; ++m)
          wf[m] = (kk == 0) ? wpre[m]
                            : *(const s16x8*)(w2p + (size_t)(16 * m) * HIDD + kk * 32);
        #pragma unroll
        for (int np = 0; np < 4; ++np)
          hf[np] = *(const s16x8*)(S + hb + (uint32_t)(16 * np + lq) * 384u
                                   + (((uint32_t)(64 * kk + 16 * lg)) ^ xsw));
        #pragma unroll
        for (int np = 0; np < 4; ++np)
          #pragma unroll
          for (int m = 0; m < 3; ++m)
            oacc[m][np] = mfma16(wf[m], hf[np], oacc[m][np]);
      }
      // no barrier: next iteration writes the other hid buffer
    }
  }

  // ---- Epilogue: gates -> regs, then oacc -> LDS transpose [c][65], coalesced store
  const f32x4 g4 = *(const f32x4*)(S + OFF_GATE + lane * 16);  // gates stable since phase 2
  __syncthreads();   // all hid reads + gate reads done; outl may overlay everything
  {
    float* outl = (float*)S;
    #pragma unroll
    for (int m = 0; m < 3; ++m)
      #pragma unroll
      for (int np = 0; np < 4; ++np){
        const int t  = 16 * np + lq;
        const int c0 = wv * 48 + 16 * m + 4 * lg;
        #pragma unroll
        for (int r = 0; r < 4; ++r)
          outl[(c0 + r) * 65 + t] = oacc[m][np][r];
      }
  }
  __syncthreads();
  {
    const int t = lane;
    const float sc = scp[0];
    const float* outl = (const float*)S;
    const float* xbt = xb + n0 + t;
    float* ob = out + (size_t)b * CC * NN + n0 + t;
    #pragma unroll 4
    for (int j = 0; j < 48; ++j){
      const int c = wv * 48 + j;
      const float o  = outl[c * 65 + t];
      const float bt = __builtin_fmaf(g4[0], b2[c],
                        __builtin_fmaf(g4[1], b2[CC + c],
                         __builtin_fmaf(g4[2], b2[2 * CC + c], g4[3] * b2[3 * CC + c])));
      const float xv = xbt[(size_t)c * NN];
      ob[(size_t)c * NN] = __builtin_fmaf(sc, o + bt, xv);
    }
  }
}

extern "C" void kernel_launch(void* const* d_in, const int* in_sizes, int n_in,
                              void* d_out, int out_size, void* d_ws, size_t ws_size,
                              hipStream_t stream){
  const float* x  = (const float*)d_in[0];
  const float* rw = (const float*)d_in[1];
  const float* rb = (const float*)d_in[2];
  const float* w1 = (const float*)d_in[3];
  const float* b1 = (const float*)d_in[4];
  const float* w2 = (const float*)d_in[5];
  const float* b2 = (const float*)d_in[6];
  const float* sc = (const float*)d_in[7];
  float* out = (float*)d_out;
  uint16_t* w1b = (uint16_t*)d_ws;
  uint16_t* w2b = w1b + 294912;

  hipLaunchKernelGGL(kconv, dim3(1152), dim3(256), 0, stream, w1, w2, w1b, w2b);
  hipLaunchKernelGGL(kmoe,  dim3(2048), dim3(256), LDS_SZ, stream,
                     x, rw, rb, w1b, b1, w2b, b2, sc, out);
}

// Round 4
// 348.263 us; speedup vs baseline: 1.5534x; 1.5534x over previous
//
#include <hip/hip_runtime.h>
#include <stdint.h>

typedef __attribute__((ext_vector_type(4))) float f32x4;
typedef __attribute__((ext_vector_type(8))) short s16x8;

#define CC   192
#define NN   16384
#define EE   4
#define HIDD 384

// LDS map (dynamic, 50176 B) -> 3 blocks/CU by LDS:
//  [0,     24576)  X tile [64][192] bf16 swizzled; AFTER frag hoist reused as hid buf0
//  [24576, 49152)  router partials (phase 1-2 only), then hid buf1
//  [49152, 50176)  gates [64 tok][4 e] f32
//  epilogue: outl [192 c][65 tok] f32 = 49920 B overlays everything (gates read to regs first)
// NOTE: launch_bounds min-waves MUST stay 2 — declaring 3 caps unified VGPRs
// and spills the 96-VGPR xf hoist to scratch (round 3: FETCH 115->816 MB, 616 us).
#define OFF_H0   0u
#define OFF_H1   24576u
#define OFF_PART 24576
#define OFF_GATE 49152
#define LDS_SZ   50176

__device__ __forceinline__ uint16_t bfbits(float f){
  uint32_t u = __builtin_bit_cast(uint32_t, f);
  u += 0x7FFFu + ((u >> 16) & 1u);
  return (uint16_t)(u >> 16);
}
__device__ __forceinline__ uint32_t pkbf(float lo, float hi){
  uint32_t ul = __builtin_bit_cast(uint32_t, lo);
  uint32_t uh = __builtin_bit_cast(uint32_t, hi);
  ul += 0x7FFFu + ((ul >> 16) & 1u);
  uh += 0x7FFFu + ((uh >> 16) & 1u);
  return (ul >> 16) | (uh & 0xFFFF0000u);
}
// tanh-form GELU, |err| <= ~3e-3 (threshold 0.109; measured absmax 0.031 with this)
__device__ __forceinline__ float gelu_f(float v){
  float x2 = v * v;
  float z = v * __builtin_fmaf(x2, -0.1029432f, -2.3022082f);
  float e = __builtin_amdgcn_exp2f(z);
  return v * __builtin_amdgcn_rcpf(1.0f + e);
}
__device__ __forceinline__ f32x4 mfma16(s16x8 a, s16x8 b, f32x4 c){
  asm("v_mfma_f32_16x16x32_bf16 %0, %1, %2, %0" : "+v"(c) : "v"(a), "v"(b));
  return c;
}

extern "C" __global__ void kconv(const float* __restrict__ w1, const float* __restrict__ w2,
                                 uint16_t* __restrict__ w1b, uint16_t* __restrict__ w2b){
  int i = blockIdx.x * 256 + threadIdx.x;
  w1b[i] = bfbits(w1[i]);
  w2b[i] = bfbits(w2[i]);
}

// 1 block = 64 tokens, 256 threads = 4 waves; waves split the feature dim.
// A-operand = weights, B-operand = activations; D = [feature][token].
__global__ __launch_bounds__(256, 2) void kmoe(
    const float* __restrict__ x, const float* __restrict__ rw,
    const float* __restrict__ rb, const uint16_t* __restrict__ w1b,
    const float* __restrict__ b1, const uint16_t* __restrict__ w2b,
    const float* __restrict__ b2, const float* __restrict__ scp,
    float* __restrict__ out)
{
  extern __shared__ __align__(16) unsigned char S[];
  const int tid  = threadIdx.x;
  const int lane = tid & 63;
  const int wv   = tid >> 6;
  const int lq   = lane & 15;
  const int lg   = lane >> 4;
  const int tile = blockIdx.x;
  const int b    = tile >> 8;
  const int n0   = (tile & 255) << 6;
  const float* xb = x + (size_t)b * CC * NN;

  // ---- Phase 1: stage X tile (bf16, swizzled) + fp32 router partials
  {
    const int t = lane;
    const uint32_t rowb = (uint32_t)t * 384u;
    const uint32_t sw   = ((uint32_t)(t & 7)) << 4;
    float a0 = 0.f, a1 = 0.f, a2 = 0.f, a3 = 0.f;
    #pragma unroll 8
    for (int j = 0; j < 48; j += 2){
      const int c = wv * 48 + j;
      const float v0 = xb[(size_t)c * NN + n0 + t];
      const float v1 = xb[(size_t)(c + 1) * NN + n0 + t];
      a0 = __builtin_fmaf(v1, rw[c + 1],          __builtin_fmaf(v0, rw[c],          a0));
      a1 = __builtin_fmaf(v1, rw[CC + c + 1],     __builtin_fmaf(v0, rw[CC + c],     a1));
      a2 = __builtin_fmaf(v1, rw[2 * CC + c + 1], __builtin_fmaf(v0, rw[2 * CC + c], a2));
      a3 = __builtin_fmaf(v1, rw[3 * CC + c + 1], __builtin_fmaf(v0, rw[3 * CC + c], a3));
      *(uint32_t*)(S + rowb + (((uint32_t)(2 * c)) ^ sw)) = pkbf(v0, v1);
    }
    float* pl = (float*)(S + OFF_PART);
    pl[(wv * 4 + 0) * 64 + t] = a0;
    pl[(wv * 4 + 1) * 64 + t] = a1;
    pl[(wv * 4 + 2) * 64 + t] = a2;
    pl[(wv * 4 + 3) * 64 + t] = a3;
  }
  __syncthreads();

  // ---- Phase 2 (tid<64): router finalize -> gates
  if (tid < 64){
    const int t = tid;
    const float* pl = (const float*)(S + OFF_PART);
    float l0 = rb[0], l1 = rb[1], l2 = rb[2], l3 = rb[3];
    #pragma unroll
    for (int cg = 0; cg < 4; ++cg){
      l0 += pl[(cg * 4 + 0) * 64 + t];
      l1 += pl[(cg * 4 + 1) * 64 + t];
      l2 += pl[(cg * 4 + 2) * 64 + t];
      l3 += pl[(cg * 4 + 3) * 64 + t];
    }
    int i1 = 0; float v1 = l0;
    if (l1 > v1){ v1 = l1; i1 = 1; }
    if (l2 > v1){ v1 = l2; i1 = 2; }
    if (l3 > v1){ v1 = l3; i1 = 3; }
    float v2 = -3.0e38f; int i2 = 0;
    if (i1 != 0){ v2 = l0; i2 = 0; }
    if (i1 != 1 && l1 > v2){ v2 = l1; i2 = 1; }
    if (i1 != 2 && l2 > v2){ v2 = l2; i2 = 2; }
    if (i1 != 3 && l3 > v2){ v2 = l3; i2 = 3; }
    const float ex = __expf(v2 - v1);
    const float ga = 1.0f / (1.0f + ex);
    const float gb = ex * ga;
    float* glw = (float*)(S + OFF_GATE);
    glw[t * 4 + 0] = (i1 == 0) ? ga : ((i2 == 0) ? gb : 0.0f);
    glw[t * 4 + 1] = (i1 == 1) ? ga : ((i2 == 1) ? gb : 0.0f);
    glw[t * 4 + 2] = (i1 == 2) ? ga : ((i2 == 2) ? gb : 0.0f);
    glw[t * 4 + 3] = (i1 == 3) ? ga : ((i2 == 3) ? gb : 0.0f);
  }

  // X B-fragments -> registers (invariant across all (e,ch)): 24 x s16x8 = 96 VGPR
  const uint32_t xsw = ((uint32_t)(lq & 7)) << 4;
  s16x8 xf[4][6];
  #pragma unroll
  for (int np = 0; np < 4; ++np){
    const uint32_t rowb = (uint32_t)(16 * np + lq) * 384u;
    #pragma unroll
    for (int kk = 0; kk < 6; ++kk)
      xf[np][kk] = *(const s16x8*)(S + rowb + (((uint32_t)(64 * kk + 16 * lg)) ^ xsw));
  }
  __syncthreads();   // X reads + partials reads done -> regions reusable as hid bufs

  // ---- Main loop: 8 iterations (e x ch), 1 barrier each (hid double-buffered)
  const float* gl = (const float*)(S + OFF_GATE);
  const uint16_t* w1t = w1b + (size_t)(wv * 48 + lq) * CC   + 8 * lg;
  const uint16_t* w2t = w2b + (size_t)(wv * 48 + lq) * HIDD + 8 * lg;

  f32x4 oacc[3][4];
  #pragma unroll
  for (int m = 0; m < 3; ++m)
    #pragma unroll
    for (int np = 0; np < 4; ++np)
      oacc[m][np] = (f32x4){0.f, 0.f, 0.f, 0.f};

  #pragma unroll 1
  for (int e = 0; e < EE; ++e){
    float gt[4];
    #pragma unroll
    for (int np = 0; np < 4; ++np) gt[np] = gl[(16 * np + lq) * 4 + e];
    #pragma unroll 1
    for (int ch = 0; ch < 2; ++ch){
      const uint32_t hb = ((e * 2 + ch) & 1) ? OFF_H1 : OFF_H0;
      // GEMM1: hacc[hid-tile][tok-tile], init from fc1 bias (4 consecutive features/lane)
      f32x4 hacc[3][4];
      #pragma unroll
      for (int m = 0; m < 3; ++m){
        const f32x4 bv = *(const f32x4*)(b1 + e * HIDD + ch * 192 + wv * 48 + 16 * m + 4 * lg);
        #pragma unroll
        for (int np = 0; np < 4; ++np) hacc[m][np] = bv;
      }
      const uint16_t* w1p = w1t + (size_t)(e * HIDD + ch * 192) * CC;
      #pragma unroll
      for (int kk = 0; kk < 6; ++kk){
        s16x8 wf[3];
        #pragma unroll
        for (int m = 0; m < 3; ++m)
          wf[m] = *(const s16x8*)(w1p + (size_t)(16 * m) * CC + kk * 32);
        #pragma unroll
        for (int np = 0; np < 4; ++np)
          #pragma unroll
          for (int m = 0; m < 3; ++m)
            hacc[m][np] = mfma16(wf[m], xf[np][kk], hacc[m][np]);
      }
      // Prefetch GEMM2 kk=0 weight frags: L2 latency hides under gelu + barrier
      const uint16_t* w2p = w2t + (size_t)(e * CC) * HIDD + ch * 192;
      s16x8 wpre[3];
      #pragma unroll
      for (int m = 0; m < 3; ++m)
        wpre[m] = *(const s16x8*)(w2p + (size_t)(16 * m) * HIDD);
      // GELU * gate -> hid LDS (b64 writes: 4 consecutive features per lane)
      #pragma unroll
      for (int np = 0; np < 4; ++np){
        const uint32_t tb = hb + (uint32_t)(16 * np + lq) * 384u;
        const float g = gt[np];
        #pragma unroll
        for (int m = 0; m < 3; ++m){
          const float v0 = gelu_f(hacc[m][np][0]) * g;
          const float v1 = gelu_f(hacc[m][np][1]) * g;
          const float v2 = gelu_f(hacc[m][np][2]) * g;
          const float v3 = gelu_f(hacc[m][np][3]) * g;
          uint2 p; p.x = pkbf(v0, v1); p.y = pkbf(v2, v3);
          *(uint2*)(S + tb + (((uint32_t)(96 * wv + 32 * m + 8 * lg)) ^ xsw)) = p;
        }
      }
      __syncthreads();
      // GEMM2: A = fc2 rows (C channels), B = hid from LDS
      #pragma unroll
      for (int kk = 0; kk < 6; ++kk){
        s16x8 wf[3], hf[4];
        #pragma unroll
        for (int m = 0; m < 3; ++m)
          wf[m] = (kk == 0) ? wpre[m]
                            : *(const s16x8*)(w2p + (size_t)(16 * m) * HIDD + kk * 32);
        #pragma unroll
        for (int np = 0; np < 4; ++np)
          hf[np] = *(const s16x8*)(S + hb + (uint32_t)(16 * np + lq) * 384u
                                   + (((uint32_t)(64 * kk + 16 * lg)) ^ xsw));
        #pragma unroll
        for (int np = 0; np < 4; ++np)
          #pragma unroll
          for (int m = 0; m < 3; ++m)
            oacc[m][np] = mfma16(wf[m], hf[np], oacc[m][np]);
      }
      // no barrier: next iteration writes the other hid buffer
    }
  }

  // ---- Epilogue: gates -> regs, then oacc -> LDS transpose [c][65], coalesced store
  const f32x4 g4 = *(const f32x4*)(S + OFF_GATE + lane * 16);  // gates stable since phase 2
  __syncthreads();   // all hid reads + gate reads done; outl may overlay everything
  {
    float* outl = (float*)S;
    #pragma unroll
    for (int m = 0; m < 3; ++m)
      #pragma unroll
      for (int np = 0; np < 4; ++np){
        const int t  = 16 * np + lq;
        const int c0 = wv * 48 + 16 * m + 4 * lg;
        #pragma unroll
        for (int r = 0; r < 4; ++r)
          outl[(c0 + r) * 65 + t] = oacc[m][np][r];
      }
  }
  __syncthreads();
  {
    const int t = lane;
    const float sc = scp[0];
    const float* outl = (const float*)S;
    const float* xbt = xb + n0 + t;
    float* ob = out + (size_t)b * CC * NN + n0 + t;
    #pragma unroll 4
    for (int j = 0; j < 48; ++j){
      const int c = wv * 48 + j;
      const float o  = outl[c * 65 + t];
      const float bt = __builtin_fmaf(g4[0], b2[c],
                        __builtin_fmaf(g4[1], b2[CC + c],
                         __builtin_fmaf(g4[2], b2[2 * CC + c], g4[3] * b2[3 * CC + c])));
      const float xv = xbt[(size_t)c * NN];
      ob[(size_t)c * NN] = __builtin_fmaf(sc, o + bt, xv);
    }
  }
}

extern "C" void kernel_launch(void* const* d_in, const int* in_sizes, int n_in,
                              void* d_out, int out_size, void* d_ws, size_t ws_size,
                              hipStream_t stream){
  const float* x  = (const float*)d_in[0];
  const float* rw = (const float*)d_in[1];
  const float* rb = (const float*)d_in[2];
  const float* w1 = (const float*)d_in[3];
  const float* b1 = (const float*)d_in[4];
  const float* w2 = (const float*)d_in[5];
  const float* b2 = (const float*)d_in[6];
  const float* sc = (const float*)d_in[7];
  float* out = (float*)d_out;
  uint16_t* w1b = (uint16_t*)d_ws;
  uint16_t* w2b = w1b + 294912;

  hipLaunchKernelGGL(kconv, dim3(1152), dim3(256), 0, stream, w1, w2, w1b, w2b);
  hipLaunchKernelGGL(kmoe,  dim3(2048), dim3(256), LDS_SZ, stream,
                     x, rw, rb, w1b, b1, w2b, b2, sc, out);
}

// Round 5
// 346.002 us; speedup vs baseline: 1.5635x; 1.0065x over previous
//
#include <hip/hip_runtime.h>
#include <stdint.h>

typedef __attribute__((ext_vector_type(4))) float f32x4;
typedef __attribute__((ext_vector_type(8))) short s16x8;

#define CC   192
#define NN   16384
#define EE   4
#define HIDD 384

// LDS map (dynamic, 50176 B) -> 3 blocks/CU by LDS:
//  [0,     24576)  X tile [64 tok][192 ch] bf16, XOR-swizzled — resident whole kernel
//  [24576, 49152)  router partials (phase 1-2), then SINGLE hid buffer [64][192] bf16
//  [49152, 50176)  gates [64 tok][4 e] f32
//  epilogue: outl [192 c][65 tok] f32 = 49920 B overlays X+hid (gates to regs first)
// Register budget theory (round 4): trace VGPR_Count excludes AGPR side of the
// unified file; the old 96-reg xf hoist put total ~224/wave -> 9 waves -> 2
// blocks/CU no matter what LDS did. This version targets ~150 total so LDS (3
// blocks) is the binding limit. launch_bounds(256,3) caps alloc at 170.
#define OFF_HID  24576u
#define OFF_PART 24576
#define OFF_GATE 49152
#define LDS_SZ   50176

__device__ __forceinline__ uint16_t bfbits(float f){
  uint32_t u = __builtin_bit_cast(uint32_t, f);
  u += 0x7FFFu + ((u >> 16) & 1u);
  return (uint16_t)(u >> 16);
}
__device__ __forceinline__ uint32_t pkbf(float lo, float hi){
  uint32_t ul = __builtin_bit_cast(uint32_t, lo);
  uint32_t uh = __builtin_bit_cast(uint32_t, hi);
  ul += 0x7FFFu + ((ul >> 16) & 1u);
  uh += 0x7FFFu + ((uh >> 16) & 1u);
  return (ul >> 16) | (uh & 0xFFFF0000u);
}
// tanh-form GELU, |err| <= ~3e-3 (threshold 0.109; measured absmax 0.031)
__device__ __forceinline__ float gelu_f(float v){
  float x2 = v * v;
  float z = v * __builtin_fmaf(x2, -0.1029432f, -2.3022082f);
  float e = __builtin_amdgcn_exp2f(z);
  return v * __builtin_amdgcn_rcpf(1.0f + e);
}
// Builtin (not inline asm): scheduler-visible so weight/LDS loads pipeline
// around the MFMAs and accumulators live cleanly in the unified VGPR/AGPR file.
__device__ __forceinline__ f32x4 mfma16(s16x8 a, s16x8 b, f32x4 c){
  return __builtin_amdgcn_mfma_f32_16x16x32_bf16(a, b, c, 0, 0, 0);
}

extern "C" __global__ void kconv(const float* __restrict__ w1, const float* __restrict__ w2,
                                 uint16_t* __restrict__ w1b, uint16_t* __restrict__ w2b){
  int i = blockIdx.x * 256 + threadIdx.x;
  w1b[i] = bfbits(w1[i]);
  w2b[i] = bfbits(w2[i]);
}

// 1 block = 64 tokens, 256 threads = 4 waves; waves split the feature dim.
// A-operand = weights, B-operand = activations; D = [feature][token].
__global__ __launch_bounds__(256, 3) void kmoe(
    const float* __restrict__ x, const float* __restrict__ rw,
    const float* __restrict__ rb, const uint16_t* __restrict__ w1b,
    const float* __restrict__ b1, const uint16_t* __restrict__ w2b,
    const float* __restrict__ b2, const float* __restrict__ scp,
    float* __restrict__ out)
{
  extern __shared__ __align__(16) unsigned char S[];
  const int tid  = threadIdx.x;
  const int lane = tid & 63;
  const int wv   = tid >> 6;
  const int lq   = lane & 15;
  const int lg   = lane >> 4;
  const int tile = blockIdx.x;
  const int b    = tile >> 8;
  const int n0   = (tile & 255) << 6;
  const float* xb = x + (size_t)b * CC * NN;

  // ---- Phase 1: stage X tile (bf16, swizzled) + fp32 router partials
  {
    const int t = lane;
    const uint32_t rowbp = (uint32_t)t * 384u;
    const uint32_t sw    = ((uint32_t)(t & 7)) << 4;
    float a0 = 0.f, a1 = 0.f, a2 = 0.f, a3 = 0.f;
    #pragma unroll 8
    for (int j = 0; j < 48; j += 2){
      const int c = wv * 48 + j;
      const float v0 = xb[(size_t)c * NN + n0 + t];
      const float v1 = xb[(size_t)(c + 1) * NN + n0 + t];
      a0 = __builtin_fmaf(v1, rw[c + 1],          __builtin_fmaf(v0, rw[c],          a0));
      a1 = __builtin_fmaf(v1, rw[CC + c + 1],     __builtin_fmaf(v0, rw[CC + c],     a1));
      a2 = __builtin_fmaf(v1, rw[2 * CC + c + 1], __builtin_fmaf(v0, rw[2 * CC + c], a2));
      a3 = __builtin_fmaf(v1, rw[3 * CC + c + 1], __builtin_fmaf(v0, rw[3 * CC + c], a3));
      *(uint32_t*)(S + rowbp + (((uint32_t)(2 * c)) ^ sw)) = pkbf(v0, v1);
    }
    float* pl = (float*)(S + OFF_PART);
    pl[(wv * 4 + 0) * 64 + t] = a0;
    pl[(wv * 4 + 1) * 64 + t] = a1;
    pl[(wv * 4 + 2) * 64 + t] = a2;
    pl[(wv * 4 + 3) * 64 + t] = a3;
  }
  __syncthreads();

  // ---- Phase 2 (tid<64): router finalize -> gates
  if (tid < 64){
    const int t = tid;
    const float* pl = (const float*)(S + OFF_PART);
    float l0 = rb[0], l1 = rb[1], l2 = rb[2], l3 = rb[3];
    #pragma unroll
    for (int cg = 0; cg < 4; ++cg){
      l0 += pl[(cg * 4 + 0) * 64 + t];
      l1 += pl[(cg * 4 + 1) * 64 + t];
      l2 += pl[(cg * 4 + 2) * 64 + t];
      l3 += pl[(cg * 4 + 3) * 64 + t];
    }
    int i1 = 0; float v1 = l0;
    if (l1 > v1){ v1 = l1; i1 = 1; }
    if (l2 > v1){ v1 = l2; i1 = 2; }
    if (l3 > v1){ v1 = l3; i1 = 3; }
    float v2 = -3.0e38f; int i2 = 0;
    if (i1 != 0){ v2 = l0; i2 = 0; }
    if (i1 != 1 && l1 > v2){ v2 = l1; i2 = 1; }
    if (i1 != 2 && l2 > v2){ v2 = l2; i2 = 2; }
    if (i1 != 3 && l3 > v2){ v2 = l3; i2 = 3; }
    const float ex = __expf(v2 - v1);
    const float ga = 1.0f / (1.0f + ex);
    const float gb = ex * ga;
    float* glw = (float*)(S + OFF_GATE);
    glw[t * 4 + 0] = (i1 == 0) ? ga : ((i2 == 0) ? gb : 0.0f);
    glw[t * 4 + 1] = (i1 == 1) ? ga : ((i2 == 1) ? gb : 0.0f);
    glw[t * 4 + 2] = (i1 == 2) ? ga : ((i2 == 2) ? gb : 0.0f);
    glw[t * 4 + 3] = (i1 == 3) ? ga : ((i2 == 3) ? gb : 0.0f);
  }
  __syncthreads();   // gates + partials settled; X stable in LDS from here on

  // ---- Main loop: 8 iterations (e x ch); X read from LDS per kk (no hoist)
  const float* gl = (const float*)(S + OFF_GATE);
  const uint16_t* w1t = w1b + (size_t)(wv * 48 + lq) * CC   + 8 * lg;
  const uint16_t* w2t = w2b + (size_t)(wv * 48 + lq) * HIDD + 8 * lg;
  const uint32_t xsw = ((uint32_t)(lq & 7)) << 4;
  uint32_t rowb[4];
  #pragma unroll
  for (int np = 0; np < 4; ++np) rowb[np] = (uint32_t)(16 * np + lq) * 384u;

  f32x4 oacc[3][4];
  #pragma unroll
  for (int m = 0; m < 3; ++m)
    #pragma unroll
    for (int np = 0; np < 4; ++np)
      oacc[m][np] = (f32x4){0.f, 0.f, 0.f, 0.f};

  #pragma unroll 1
  for (int e = 0; e < EE; ++e){
    float gt[4];
    #pragma unroll
    for (int np = 0; np < 4; ++np) gt[np] = gl[(16 * np + lq) * 4 + e];
    #pragma unroll 1
    for (int ch = 0; ch < 2; ++ch){
      // GEMM1: hacc[feat-tile][tok-tile], bias-init; weights double-buffered
      f32x4 hacc[3][4];
      #pragma unroll
      for (int m = 0; m < 3; ++m){
        const f32x4 bv = *(const f32x4*)(b1 + e * HIDD + ch * 192 + wv * 48 + 16 * m + 4 * lg);
        #pragma unroll
        for (int np = 0; np < 4; ++np) hacc[m][np] = bv;
      }
      const uint16_t* w1p = w1t + (size_t)(e * HIDD + ch * 192) * CC;
      s16x8 wf[3], wn[3];
      #pragma unroll
      for (int m = 0; m < 3; ++m) wf[m] = *(const s16x8*)(w1p + (size_t)(16 * m) * CC);
      #pragma unroll
      for (int kk = 0; kk < 6; ++kk){
        #pragma unroll
        for (int m = 0; m < 3; ++m)
          wn[m] = (kk < 5) ? *(const s16x8*)(w1p + (size_t)(16 * m) * CC + (kk + 1) * 32)
                           : wf[m];
        s16x8 xk[4];
        #pragma unroll
        for (int np = 0; np < 4; ++np)
          xk[np] = *(const s16x8*)(S + rowb[np] + (((uint32_t)(64 * kk + 16 * lg)) ^ xsw));
        #pragma unroll
        for (int np = 0; np < 4; ++np)
          #pragma unroll
          for (int m = 0; m < 3; ++m)
            hacc[m][np] = mfma16(wf[m], xk[np], hacc[m][np]);
        #pragma unroll
        for (int m = 0; m < 3; ++m) wf[m] = wn[m];
      }
      __syncthreads();   // barrier A: prior iteration's GEMM2 hid reads complete
      // GELU * gate -> hid LDS (b64 writes: 4 consecutive features per lane)
      #pragma unroll
      for (int np = 0; np < 4; ++np){
        const uint32_t tb = OFF_HID + rowb[np];
        const float g = gt[np];
        #pragma unroll
        for (int m = 0; m < 3; ++m){
          const float v0 = gelu_f(hacc[m][np][0]) * g;
          const float v1 = gelu_f(hacc[m][np][1]) * g;
          const float v2 = gelu_f(hacc[m][np][2]) * g;
          const float v3 = gelu_f(hacc[m][np][3]) * g;
          uint2 p; p.x = pkbf(v0, v1); p.y = pkbf(v2, v3);
          *(uint2*)(S + tb + (((uint32_t)(96 * wv + 32 * m + 8 * lg)) ^ xsw)) = p;
        }
      }
      __syncthreads();   // barrier B: hid tile ready
      // GEMM2: A = fc2 rows, B = hid (LDS); weights double-buffered
      const uint16_t* w2p = w2t + (size_t)(e * CC) * HIDD + ch * 192;
      #pragma unroll
      for (int m = 0; m < 3; ++m) wf[m] = *(const s16x8*)(w2p + (size_t)(16 * m) * HIDD);
      #pragma unroll
      for (int kk = 0; kk < 6; ++kk){
        #pragma unroll
        for (int m = 0; m < 3; ++m)
          wn[m] = (kk < 5) ? *(const s16x8*)(w2p + (size_t)(16 * m) * HIDD + (kk + 1) * 32)
                           : wf[m];
        s16x8 hf[4];
        #pragma unroll
        for (int np = 0; np < 4; ++np)
          hf[np] = *(const s16x8*)(S + OFF_HID + rowb[np]
                                   + (((uint32_t)(64 * kk + 16 * lg)) ^ xsw));
        #pragma unroll
        for (int np = 0; np < 4; ++np)
          #pragma unroll
          for (int m = 0; m < 3; ++m)
            oacc[m][np] = mfma16(wf[m], hf[np], oacc[m][np]);
        #pragma unroll
        for (int m = 0; m < 3; ++m) wf[m] = wn[m];
      }
      // no trailing barrier: next iteration's barrier A protects the hid buffer
    }
  }

  // ---- Epilogue: gates -> regs, oacc -> LDS transpose [c][65], coalesced store
  const f32x4 g4 = *(const f32x4*)(S + OFF_GATE + lane * 16);
  __syncthreads();   // all hid reads + gate reads done; outl overlays X+hid+gates
  {
    float* outl = (float*)S;
    #pragma unroll
    for (int m = 0; m < 3; ++m)
      #pragma unroll
      for (int np = 0; np < 4; ++np){
        const int t  = 16 * np + lq;
        const int c0 = wv * 48 + 16 * m + 4 * lg;
        #pragma unroll
        for (int r = 0; r < 4; ++r)
          outl[(c0 + r) * 65 + t] = oacc[m][np][r];
      }
  }
  __syncthreads();
  {
    const int t = lane;
    const float sc = scp[0];
    const float* outl = (const float*)S;
    const float* xbt = xb + n0 + t;
    float* ob = out + (size_t)b * CC * NN + n0 + t;
    #pragma unroll 4
    for (int j = 0; j < 48; ++j){
      const int c = wv * 48 + j;
      const float o  = outl[c * 65 + t];
      const float bt = __builtin_fmaf(g4[0], b2[c],
                        __builtin_fmaf(g4[1], b2[CC + c],
                         __builtin_fmaf(g4[2], b2[2 * CC + c], g4[3] * b2[3 * CC + c])));
      const float xv = xbt[(size_t)c * NN];
      ob[(size_t)c * NN] = __builtin_fmaf(sc, o + bt, xv);
    }
  }
}

extern "C" void kernel_launch(void* const* d_in, const int* in_sizes, int n_in,
                              void* d_out, int out_size, void* d_ws, size_t ws_size,
                              hipStream_t stream){
  const float* x  = (const float*)d_in[0];
  const float* rw = (const float*)d_in[1];
  const float* rb = (const float*)d_in[2];
  const float* w1 = (const float*)d_in[3];
  const float* b1 = (const float*)d_in[4];
  const float* w2 = (const float*)d_in[5];
  const float* b2 = (const float*)d_in[6];
  const float* sc = (const float*)d_in[7];
  float* out = (float*)d_out;
  uint16_t* w1b = (uint16_t*)d_ws;
  uint16_t* w2b = w1b + 294912;

  hipLaunchKernelGGL(kconv, dim3(1152), dim3(256), 0, stream, w1, w2, w1b, w2b);
  hipLaunchKernelGGL(kmoe,  dim3(2048), dim3(256), LDS_SZ, stream,
                     x, rw, rb, w1b, b1, w2b, b2, sc, out);
}